// Round 6
// baseline (282.538 us; speedup 1.0000x reference)
//
#include <hip/hip_runtime.h>
#include <hip/hip_bf16.h>
#include <math.h>

// Problem constants
#define NN 30000
#define NE 480000
#define FIN 256
#define DH 32
#define NH 4
#define NC 47

typedef __attribute__((ext_vector_type(8))) short frag_ab;  // 8 bf16 (4 VGPR)
typedef __attribute__((ext_vector_type(4))) float f32x4;    // MFMA 16x16 accum
typedef __hip_bfloat16 bf16;

static inline size_t align256(size_t x) { return (x + 255) & ~(size_t)255; }

__device__ __forceinline__ short f2bf(float f) {
    union { float f; unsigned u; } c; c.f = f;
    unsigned r = (c.u + 0x7FFFu + ((c.u >> 16) & 1u)) >> 16;  // RNE
    return (short)r;
}

__device__ __forceinline__ float selh(float4 e, int h) {
    return (h == 0) ? e.x : (h == 1) ? e.y : (h == 2) ? e.z : e.w;
}

// ---------------- CSR build ----------------
__global__ void count_k(const int* __restrict__ dst, int* __restrict__ cnt, int E) {
    int e = blockIdx.x * blockDim.x + threadIdx.x;
    if (e < E) atomicAdd(&cnt[dst[e]], 1);
}

// exclusive scan; writes offs[0..n] AND cursor[0..n-1] (fill cursors)
__global__ __launch_bounds__(1024) void scan_k(const int* __restrict__ cnt,
                                               int* __restrict__ offs,
                                               int* __restrict__ cursor, int n) {
    __shared__ int warp_sums[16];
    __shared__ int carry_s;
    const int lane = threadIdx.x & 63;
    const int wid = threadIdx.x >> 6;
    if (threadIdx.x == 0) carry_s = 0;
    __syncthreads();
    for (int base = 0; base < n; base += 1024) {
        int i = base + threadIdx.x;
        int v = (i < n) ? cnt[i] : 0;
        int x = v;
        #pragma unroll
        for (int off = 1; off < 64; off <<= 1) {
            int y = __shfl_up(x, off);
            if (lane >= off) x += y;
        }
        if (lane == 63) warp_sums[wid] = x;
        __syncthreads();
        if (wid == 0) {
            int ws = (lane < 16) ? warp_sums[lane] : 0;
            #pragma unroll
            for (int off = 1; off < 16; off <<= 1) {
                int y = __shfl_up(ws, off);
                if (lane >= off) ws += y;
            }
            if (lane < 16) warp_sums[lane] = ws;
        }
        __syncthreads();
        int wbase = (wid > 0) ? warp_sums[wid - 1] : 0;
        int incl = x + wbase + carry_s;
        if (i < n) {
            offs[i] = incl - v;  // exclusive
            cursor[i] = incl - v;
        }
        __syncthreads();
        if (threadIdx.x == 1023) carry_s = incl;
        __syncthreads();
    }
    if (threadIdx.x == 0) offs[n] = carry_s;
}

// srcs[slot] = src id, in CSR-by-dst order
__global__ void fill_k(const int* __restrict__ dst, const int* __restrict__ src,
                       int* __restrict__ cursor, int* __restrict__ srcs, int E) {
    int e = blockIdx.x * blockDim.x + threadIdx.x;
    if (e < E) {
        int p = atomicAdd(&cursor[dst[e]], 1);
        srcs[p] = src[e];
    }
}

// ---- weight prep: transposed bf16 weights, extended with el/er projection rows ----
// Layout: rows 0..M-1 = W^T; rows M..M+H-1 = W·al (head h); rows M+H..M+2H-1 = W·ar;
// remaining rows zero.  (For res weights: plain transpose + zero pad.)
__global__ void prep_w_all(const float* __restrict__ W0, const float* __restrict__ W1,
                           const float* __restrict__ rW1, const float* __restrict__ W2,
                           const float* __restrict__ rW2,
                           const float* __restrict__ al0, const float* __restrict__ ar0,
                           const float* __restrict__ al1, const float* __restrict__ ar1,
                           const float* __restrict__ al2, const float* __restrict__ ar2,
                           bf16* __restrict__ W0t, bf16* __restrict__ W1t,
                           bf16* __restrict__ rW1t, bf16* __restrict__ W2t,
                           bf16* __restrict__ rW2t) {
    const float *W, *al, *ar; bf16* Wt; int K, M, rows, H, D;
    switch (blockIdx.y) {
        case 0: W = W0;  Wt = W0t;  K = 256; M = 128; rows = 144; H = 4; D = 32; al = al0; ar = ar0; break;
        case 1: W = W1;  Wt = W1t;  K = 128; M = 128; rows = 144; H = 4; D = 32; al = al1; ar = ar1; break;
        case 2: W = rW1; Wt = rW1t; K = 128; M = 128; rows = 128; H = 0; D = 0;  al = nullptr; ar = nullptr; break;
        case 3: W = W2;  Wt = W2t;  K = 128; M = 47;  rows = 64;  H = 1; D = 47; al = al2; ar = ar2; break;
        default: W = rW2; Wt = rW2t; K = 128; M = 47; rows = 48;  H = 0; D = 0;  al = nullptr; ar = nullptr; break;
    }
    int i = blockIdx.x * 256 + threadIdx.x;
    if (i >= rows * K) return;
    int row = i / K, k = i - row * K;
    float v = 0.f;
    if (row < M) {
        v = W[(long)k * M + row];
    } else if (H > 0 && row < M + 2 * H) {
        int idx = row - M;
        int h = (idx < H) ? idx : idx - H;
        const float* a = (idx < H) ? al : ar;
        float s = 0.f;
        for (int d = 0; d < D; ++d) s += W[(long)k * M + h * D + d] * a[h * D + d];
        v = s;
    }
    Wt[i] = __float2bfloat16(v);
}

// ---- bf16 MFMA GEMM + fused attn projections ----
// C = A[N,K] @ B1t^T -> featb (bf16, cols<M), el (cols M..M+H-1), er (M+H..M+2H-1)
// optional dual: C2 (f32) = A @ B2t^T (res branch, cols<M).
// Block: 64 rows, 4 waves (wave w owns rows w*16..w*16+15).
template <bool A_F32, int NT1, int NT2, int HH>
__global__ __launch_bounds__(256) void gemm_mfma(
    const void* __restrict__ Av, const bf16* __restrict__ B1t,
    const bf16* __restrict__ B2t,
    bf16* __restrict__ C1b, float* __restrict__ el, float* __restrict__ er,
    float* __restrict__ C2, int N, int K, int M) {
    constexpr int LP = 56;  // 32 k + pad: rows 112B (16B-aligned, 2-way alias = free)
    __shared__ bf16 As[64][LP];
    __shared__ bf16 Bs1[NT1 * 16][LP];
    __shared__ bf16 Bs2[(NT2 > 0) ? NT2 * 16 : 1][LP];

    const int tid = threadIdx.x;
    const int lane = tid & 63;
    const int wid = tid >> 6;
    const int row0 = blockIdx.x * 64;
    const int l15 = lane & 15;
    const int kq = lane >> 4;          // k-quarter 0..3

    f32x4 acc1[NT1], acc2[(NT2 > 0) ? NT2 : 1];
    #pragma unroll
    for (int t = 0; t < NT1; ++t) acc1[t] = (f32x4){0.f, 0.f, 0.f, 0.f};
    if constexpr (NT2 > 0) {
        #pragma unroll
        for (int t = 0; t < NT2; ++t) acc2[t] = (f32x4){0.f, 0.f, 0.f, 0.f};
    }

    for (int k0 = 0; k0 < K; k0 += 32) {
        // stage A: 64 rows x 32 k (each thread: 8 contiguous k of one row)
        {
            const int r = tid >> 2, kk = (tid & 3) * 8;
            const int gr = row0 + r;
            if constexpr (A_F32) {
                const float* A = (const float*)Av;
                short tmp[8];
                if (gr < N) {
                    const float4 v0 = *(const float4*)&A[(long)gr * K + k0 + kk];
                    const float4 v1 = *(const float4*)&A[(long)gr * K + k0 + kk + 4];
                    tmp[0] = f2bf(v0.x); tmp[1] = f2bf(v0.y); tmp[2] = f2bf(v0.z); tmp[3] = f2bf(v0.w);
                    tmp[4] = f2bf(v1.x); tmp[5] = f2bf(v1.y); tmp[6] = f2bf(v1.z); tmp[7] = f2bf(v1.w);
                } else {
                    #pragma unroll
                    for (int j = 0; j < 8; ++j) tmp[j] = 0;
                }
                *(frag_ab*)&As[r][kk] = *(const frag_ab*)tmp;
            } else {
                const bf16* A = (const bf16*)Av;
                frag_ab v = {0, 0, 0, 0, 0, 0, 0, 0};
                if (gr < N) v = *(const frag_ab*)&A[(long)gr * K + k0 + kk];
                *(frag_ab*)&As[r][kk] = v;
            }
        }
        // stage B tiles (coalesced rows of transposed weights)
        for (int i = tid; i < NT1 * 64; i += 256) {
            const int c = i >> 2, kk = (i & 3) * 8;
            *(frag_ab*)&Bs1[c][kk] = *(const frag_ab*)&B1t[(long)c * K + k0 + kk];
        }
        if constexpr (NT2 > 0) {
            for (int i = tid; i < NT2 * 64; i += 256) {
                const int c = i >> 2, kk = (i & 3) * 8;
                *(frag_ab*)&Bs2[c][kk] = *(const frag_ab*)&B2t[(long)c * K + k0 + kk];
            }
        }
        __syncthreads();

        const frag_ab a = *(const frag_ab*)&As[wid * 16 + l15][kq * 8];
        #pragma unroll
        for (int t = 0; t < NT1; ++t) {
            const frag_ab b = *(const frag_ab*)&Bs1[t * 16 + l15][kq * 8];
            acc1[t] = __builtin_amdgcn_mfma_f32_16x16x32_bf16(a, b, acc1[t], 0, 0, 0);
        }
        if constexpr (NT2 > 0) {
            #pragma unroll
            for (int t = 0; t < NT2; ++t) {
                const frag_ab b = *(const frag_ab*)&Bs2[t * 16 + l15][kq * 8];
                acc2[t] = __builtin_amdgcn_mfma_f32_16x16x32_bf16(a, b, acc2[t], 0, 0, 0);
            }
        }
        __syncthreads();
    }

    // epilogue: D row = (lane>>4)*4 + reg, col = lane&15
    const int r0 = row0 + wid * 16 + kq * 4;
    #pragma unroll
    for (int t = 0; t < NT1; ++t) {
        const int c = t * 16 + l15;
        #pragma unroll
        for (int reg = 0; reg < 4; ++reg) {
            const int r = r0 + reg;
            if (r >= N) continue;
            const float v = acc1[t][reg];
            if (c < M) {
                C1b[(long)r * M + c] = __float2bfloat16(v);
            } else if (c < M + HH) {
                el[(long)r * HH + (c - M)] = v;
            } else if (c < M + 2 * HH) {
                er[(long)r * HH + (c - M - HH)] = v;
            }
        }
    }
    if constexpr (NT2 > 0) {
        #pragma unroll
        for (int t = 0; t < NT2; ++t) {
            const int c = t * 16 + l15;
            if (c >= M) continue;
            #pragma unroll
            for (int reg = 0; reg < 4; ++reg) {
                const int r = r0 + reg;
                if (r < N) C2[(long)r * M + c] = acc2[t][reg];
            }
        }
    }
}

// ---- edge scores e = leaky_relu(el[src]+er[dst]) -> d_out (edge order only) ----
template <int H>
__global__ void edge_e(const float* __restrict__ el, const float* __restrict__ er,
                       const int* __restrict__ src, const int* __restrict__ dst,
                       float* __restrict__ e_out, int E) {
    int e = blockIdx.x * blockDim.x + threadIdx.x;
    if (e >= E) return;
    int s = src[e], d = dst[e];
    if constexpr (H == 4) {
        float4 a = *reinterpret_cast<const float4*>(el + s * 4);
        float4 b = *reinterpret_cast<const float4*>(er + d * 4);
        float4 v;
        v.x = a.x + b.x; v.y = a.y + b.y; v.z = a.z + b.z; v.w = a.w + b.w;
        v.x = (v.x >= 0.f) ? v.x : 0.2f * v.x;
        v.y = (v.y >= 0.f) ? v.y : 0.2f * v.y;
        v.z = (v.z >= 0.f) ? v.z : 0.2f * v.z;
        v.w = (v.w >= 0.f) ? v.w : 0.2f * v.w;
        *reinterpret_cast<float4*>(e_out + e * 4) = v;
    } else {
        float v = el[s] + er[d];
        e_out[e] = (v >= 0.f) ? v : 0.2f * v;
    }
}

// ---- node-centric softmax + aggregation, one wave/node, H=4 D=32 (HD=128) ----
// Scores recomputed inline from el/er (small, cache-resident). out bf16.
template <int NELU, bool HAS_RES>
__global__ __launch_bounds__(256) void node_agg4(
    const bf16* __restrict__ featb, const float4* __restrict__ el4,
    const float4* __restrict__ er4,
    const int* __restrict__ offs, const int* __restrict__ srcs,
    const float* __restrict__ res, bf16* __restrict__ out, int n) {
    const int node = (int)((blockIdx.x * blockDim.x + threadIdx.x) >> 6);
    const int lane = threadIdx.x & 63;
    if (node >= n) return;
    const int beg = offs[node], end = offs[node + 1];
    const float4 ern = er4[node];   // wave-uniform

    // merged max+sum: per-lane online softmax over this lane's edges
    float m[4] = {-INFINITY, -INFINITY, -INFINITY, -INFINITY};
    float s[4] = {0.f, 0.f, 0.f, 0.f};
    for (int i = beg + lane; i < end; i += 64) {
        const float4 elv = el4[srcs[i]];
        float v[4] = {elv.x + ern.x, elv.y + ern.y, elv.z + ern.z, elv.w + ern.w};
        #pragma unroll
        for (int hh = 0; hh < 4; ++hh) {
            float vv = v[hh];
            vv = (vv >= 0.f) ? vv : 0.2f * vv;
            if (vv > m[hh]) {
                s[hh] = s[hh] * __expf(m[hh] - vv) + 1.f;
                m[hh] = vv;
            } else {
                s[hh] += __expf(vv - m[hh]);
            }
        }
    }
    // butterfly merge of (m,s) pairs; guard the all--inf case
    #pragma unroll
    for (int off = 32; off > 0; off >>= 1) {
        #pragma unroll
        for (int hh = 0; hh < 4; ++hh) {
            const float mo = __shfl_xor(m[hh], off);
            const float so = __shfl_xor(s[hh], off);
            const float mn = fmaxf(m[hh], mo);
            s[hh] = (mn == -INFINITY) ? 0.f
                    : s[hh] * __expf(m[hh] - mn) + so * __expf(mo - mn);
            m[hh] = mn;
        }
    }

    const int fi = lane * 2;           // two consecutive features, same head
    const int h = lane >> 4;           // fi / 32
    const float mh = (h == 0) ? m[0] : (h == 1) ? m[1] : (h == 2) ? m[2] : m[3];
    const float sh = (h == 0) ? s[0] : (h == 1) ? s[1] : (h == 2) ? s[2] : s[3];
    const float er_h = selh(ern, h);
    const float inv = 1.f / fmaxf(sh, 1e-9f);

    // aggregation: scores recomputed (broadcast loads), feat gathered
    float acc0 = 0.f, acc1 = 0.f;
    int i = beg;
    for (; i + 4 <= end; i += 4) {
        const int sn0 = srcs[i], sn1 = srcs[i + 1], sn2 = srcs[i + 2], sn3 = srcs[i + 3];
        const float4 e0 = el4[sn0], e1 = el4[sn1], e2v = el4[sn2], e3 = el4[sn3];
        float v0 = selh(e0, h) + er_h, v1 = selh(e1, h) + er_h;
        float v2 = selh(e2v, h) + er_h, v3 = selh(e3, h) + er_h;
        v0 = (v0 >= 0.f) ? v0 : 0.2f * v0;
        v1 = (v1 >= 0.f) ? v1 : 0.2f * v1;
        v2 = (v2 >= 0.f) ? v2 : 0.2f * v2;
        v3 = (v3 >= 0.f) ? v3 : 0.2f * v3;
        const __hip_bfloat162 f0 = *reinterpret_cast<const __hip_bfloat162*>(featb + (long)sn0 * 128 + fi);
        const __hip_bfloat162 f1 = *reinterpret_cast<const __hip_bfloat162*>(featb + (long)sn1 * 128 + fi);
        const __hip_bfloat162 f2 = *reinterpret_cast<const __hip_bfloat162*>(featb + (long)sn2 * 128 + fi);
        const __hip_bfloat162 f3 = *reinterpret_cast<const __hip_bfloat162*>(featb + (long)sn3 * 128 + fi);
        const float w0 = __expf(v0 - mh), w1 = __expf(v1 - mh);
        const float w2 = __expf(v2 - mh), w3 = __expf(v3 - mh);
        acc0 += w0 * __bfloat162float(f0.x); acc1 += w0 * __bfloat162float(f0.y);
        acc0 += w1 * __bfloat162float(f1.x); acc1 += w1 * __bfloat162float(f1.y);
        acc0 += w2 * __bfloat162float(f2.x); acc1 += w2 * __bfloat162float(f2.y);
        acc0 += w3 * __bfloat162float(f3.x); acc1 += w3 * __bfloat162float(f3.y);
    }
    for (; i < end; ++i) {
        const int sn = srcs[i];
        float v = selh(el4[sn], h) + er_h;
        v = (v >= 0.f) ? v : 0.2f * v;
        const float w = __expf(v - mh);
        const __hip_bfloat162 f2 = *reinterpret_cast<const __hip_bfloat162*>(featb + (long)sn * 128 + fi);
        acc0 += w * __bfloat162float(f2.x);
        acc1 += w * __bfloat162float(f2.y);
    }

    float v0 = acc0 * inv, v1 = acc1 * inv;
    if constexpr (HAS_RES) {
        const float2 rr = *reinterpret_cast<const float2*>(res + (long)node * 128 + fi);
        v0 += rr.x; v1 += rr.y;
    }
    #pragma unroll
    for (int t = 0; t < NELU; ++t) {
        v0 = (v0 > 0.f) ? v0 : expm1f(v0);
        v1 = (v1 > 0.f) ? v1 : expm1f(v1);
    }
    __hip_bfloat162 o;
    o.x = __float2bfloat16(v0);
    o.y = __float2bfloat16(v1);
    *reinterpret_cast<__hip_bfloat162*>(out + (long)node * 128 + fi) = o;
}

// ---- node-centric softmax + aggregation, H=1, HD=47 (final layer) ----
__global__ __launch_bounds__(256) void node_agg1(
    const bf16* __restrict__ featb, const float* __restrict__ el1,
    const float* __restrict__ er1,
    const int* __restrict__ offs, const int* __restrict__ srcs,
    const float* __restrict__ res, float* __restrict__ out, int n) {
    const int node = (int)((blockIdx.x * blockDim.x + threadIdx.x) >> 6);
    const int lane = threadIdx.x & 63;
    if (node >= n) return;
    const int beg = offs[node], end = offs[node + 1];
    const float ern = er1[node];

    float m = -INFINITY, s = 0.f;
    for (int i = beg + lane; i < end; i += 64) {
        float v = el1[srcs[i]] + ern;
        v = (v >= 0.f) ? v : 0.2f * v;
        if (v > m) { s = s * __expf(m - v) + 1.f; m = v; }
        else s += __expf(v - m);
    }
    #pragma unroll
    for (int off = 32; off > 0; off >>= 1) {
        const float mo = __shfl_xor(m, off);
        const float so = __shfl_xor(s, off);
        const float mn = fmaxf(m, mo);
        s = (mn == -INFINITY) ? 0.f : s * __expf(m - mn) + so * __expf(mo - mn);
        m = mn;
    }
    const float inv = 1.f / fmaxf(s, 1e-9f);

    const bool active = lane < NC;
    float acc = 0.f;
    int i = beg;
    for (; i + 4 <= end; i += 4) {
        const int sn0 = srcs[i], sn1 = srcs[i + 1], sn2 = srcs[i + 2], sn3 = srcs[i + 3];
        float v0 = el1[sn0] + ern, v1 = el1[sn1] + ern;
        float v2 = el1[sn2] + ern, v3 = el1[sn3] + ern;
        v0 = (v0 >= 0.f) ? v0 : 0.2f * v0;
        v1 = (v1 >= 0.f) ? v1 : 0.2f * v1;
        v2 = (v2 >= 0.f) ? v2 : 0.2f * v2;
        v3 = (v3 >= 0.f) ? v3 : 0.2f * v3;
        const float w0 = __expf(v0 - m), w1 = __expf(v1 - m);
        const float w2 = __expf(v2 - m), w3 = __expf(v3 - m);
        if (active) {
            acc += w0 * __bfloat162float(featb[(long)sn0 * NC + lane]);
            acc += w1 * __bfloat162float(featb[(long)sn1 * NC + lane]);
            acc += w2 * __bfloat162float(featb[(long)sn2 * NC + lane]);
            acc += w3 * __bfloat162float(featb[(long)sn3 * NC + lane]);
        }
    }
    for (; i < end; ++i) {
        const int sn = srcs[i];
        float v = el1[sn] + ern;
        v = (v >= 0.f) ? v : 0.2f * v;
        const float w = __expf(v - m);
        if (active) acc += w * __bfloat162float(featb[(long)sn * NC + lane]);
    }
    if (active) {
        out[(long)node * NC + lane] = acc * inv + res[(long)node * NC + lane];
    }
}

extern "C" void kernel_launch(void* const* d_in, const int* in_sizes, int n_in,
                              void* d_out, int out_size, void* d_ws, size_t ws_size,
                              hipStream_t stream) {
    const float* x     = (const float*)d_in[0];
    const float* W0    = (const float*)d_in[1];
    const float* al0   = (const float*)d_in[2];
    const float* ar0   = (const float*)d_in[3];
    const float* W1    = (const float*)d_in[4];
    const float* resW1 = (const float*)d_in[5];
    const float* al1   = (const float*)d_in[6];
    const float* ar1   = (const float*)d_in[7];
    const float* W2    = (const float*)d_in[8];
    const float* resW2 = (const float*)d_in[9];
    const float* al2   = (const float*)d_in[10];
    const float* ar2   = (const float*)d_in[11];
    const int*   src   = (const int*)d_in[12];
    const int*   dst   = (const int*)d_in[13];

    float* out    = (float*)d_out;
    float* logits = out;                 // [N, 47]
    float* e0     = out + (long)NN * NC; // [E, 4]
    float* e1     = e0 + (long)NE * NH;  // [E, 4]
    float* e2     = e1 + (long)NE * NH;  // [E, 1]

    char* p = (char*)d_ws;
    int* offs   = (int*)p; p += align256(sizeof(int) * (NN + 1));
    int* cursor = (int*)p; p += align256(sizeof(int) * NN);
    int* srcs   = (int*)p; p += align256(sizeof(int) * NE);
    float* el   = (float*)p; p += align256(sizeof(float) * NN * NH);
    float* er   = (float*)p; p += align256(sizeof(float) * NN * NH);
    float* resb = (float*)p; p += align256(sizeof(float) * (long)NN * 128);
    bf16* featb = (bf16*)p; p += align256(sizeof(bf16) * (long)NN * 128);
    bf16* hb    = (bf16*)p; p += align256(sizeof(bf16) * (long)NN * 128);
    bf16* W0t   = (bf16*)p; p += align256(sizeof(bf16) * 144 * 256);
    bf16* W1t   = (bf16*)p; p += align256(sizeof(bf16) * 144 * 128);
    bf16* rW1t  = (bf16*)p; p += align256(sizeof(bf16) * 128 * 128);
    bf16* W2t   = (bf16*)p; p += align256(sizeof(bf16) * 64 * 128);
    bf16* rW2t  = (bf16*)p; p += align256(sizeof(bf16) * 48 * 128);

    // ---- weight prep (transpose + fused attn-projection columns) ----
    prep_w_all<<<dim3(144, 5), 256, 0, stream>>>(W0, W1, resW1, W2, resW2,
                                                 al0, ar0, al1, ar1, al2, ar2,
                                                 W0t, W1t, rW1t, W2t, rW2t);

    // ---- CSR by dst (rebuilt every call; deterministic structure) ----
    hipMemsetAsync(cursor, 0, sizeof(int) * NN, stream);
    count_k<<<(NE + 255) / 256, 256, 0, stream>>>(dst, cursor, NE);
    scan_k<<<1, 1024, 0, stream>>>(cursor, offs, cursor, NN);
    fill_k<<<(NE + 255) / 256, 256, 0, stream>>>(dst, src, cursor, srcs, NE);

    const int gemmBlocks = (NN + 63) / 64;   // 469
    const int edgeBlocks = (NE + 255) / 256;
    const int nodeBlocks = NN / 4;           // one wave per node, 4 waves/block

    // ---- layer 0: x @ [W0|wl0|wr0] -> featb bf16 + el + er ----
    gemm_mfma<true, 9, 0, NH><<<gemmBlocks, 256, 0, stream>>>(
        x, W0t, nullptr, featb, el, er, nullptr, NN, FIN, 128);
    edge_e<NH><<<edgeBlocks, 256, 0, stream>>>(el, er, src, dst, e0, NE);
    node_agg4<1, false><<<nodeBlocks, 256, 0, stream>>>(
        featb, (const float4*)el, (const float4*)er, offs, srcs, nullptr, hb, NN);

    // ---- layer 1: hb @ [W1|wl1|wr1] + hb @ resW1 -> featb/el/er + resb ----
    gemm_mfma<false, 9, 8, NH><<<gemmBlocks, 256, 0, stream>>>(
        hb, W1t, rW1t, featb, el, er, resb, NN, 128, 128);
    edge_e<NH><<<edgeBlocks, 256, 0, stream>>>(el, er, src, dst, e1, NE);
    node_agg4<2, true><<<nodeBlocks, 256, 0, stream>>>(
        featb, (const float4*)el, (const float4*)er, offs, srcs, resb, hb, NN);

    // ---- final layer: hb @ [W2|wl2|wr2] + hb @ resW2 (M=47) ----
    gemm_mfma<false, 4, 3, 1><<<gemmBlocks, 256, 0, stream>>>(
        hb, W2t, rW2t, featb, el, er, resb, NN, 128, NC);
    edge_e<1><<<edgeBlocks, 256, 0, stream>>>(el, er, src, dst, e2, NE);
    node_agg1<<<nodeBlocks, 256, 0, stream>>>(
        featb, el, er, offs, srcs, resb, logits, NN);
}

// Round 7
// 257.101 us; speedup vs baseline: 1.0989x; 1.0989x over previous
//
#include <hip/hip_runtime.h>
#include <hip/hip_bf16.h>
#include <math.h>

// Problem constants
#define NN 30000
#define NE 480000
#define FIN 256
#define DH 32
#define NH 4
#define NC 47

typedef __attribute__((ext_vector_type(8))) short frag_ab;  // 8 bf16 (4 VGPR)
typedef __attribute__((ext_vector_type(4))) float f32x4;    // MFMA 16x16 accum
typedef __hip_bfloat16 bf16;

static inline size_t align256(size_t x) { return (x + 255) & ~(size_t)255; }

__device__ __forceinline__ short f2bf(float f) {
    union { float f; unsigned u; } c; c.f = f;
    unsigned r = (c.u + 0x7FFFu + ((c.u >> 16) & 1u)) >> 16;  // RNE
    return (short)r;
}

// ---------------- CSR build ----------------
__global__ void count_k(const int* __restrict__ dst, int* __restrict__ cnt, int E) {
    int e = blockIdx.x * blockDim.x + threadIdx.x;
    if (e < E) atomicAdd(&cnt[dst[e]], 1);
}

// exclusive scan; writes offs[0..n] AND cursor[0..n-1] (fill cursors)
__global__ __launch_bounds__(1024) void scan_k(const int* __restrict__ cnt,
                                               int* __restrict__ offs,
                                               int* __restrict__ cursor, int n) {
    __shared__ int warp_sums[16];
    __shared__ int carry_s;
    const int lane = threadIdx.x & 63;
    const int wid = threadIdx.x >> 6;
    if (threadIdx.x == 0) carry_s = 0;
    __syncthreads();
    for (int base = 0; base < n; base += 1024) {
        int i = base + threadIdx.x;
        int v = (i < n) ? cnt[i] : 0;
        int x = v;
        #pragma unroll
        for (int off = 1; off < 64; off <<= 1) {
            int y = __shfl_up(x, off);
            if (lane >= off) x += y;
        }
        if (lane == 63) warp_sums[wid] = x;
        __syncthreads();
        if (wid == 0) {
            int ws = (lane < 16) ? warp_sums[lane] : 0;
            #pragma unroll
            for (int off = 1; off < 16; off <<= 1) {
                int y = __shfl_up(ws, off);
                if (lane >= off) ws += y;
            }
            if (lane < 16) warp_sums[lane] = ws;
        }
        __syncthreads();
        int wbase = (wid > 0) ? warp_sums[wid - 1] : 0;
        int incl = x + wbase + carry_s;
        if (i < n) {
            offs[i] = incl - v;  // exclusive
            cursor[i] = incl - v;
        }
        __syncthreads();
        if (threadIdx.x == 1023) carry_s = incl;
        __syncthreads();
    }
    if (threadIdx.x == 0) offs[n] = carry_s;
}

// writes pos[e] (CSR slot of edge e) and srcs[slot] (src id in CSR order)
__global__ void fill_k(const int* __restrict__ dst, const int* __restrict__ src,
                       int* __restrict__ cursor, int* __restrict__ pos,
                       int* __restrict__ srcs, int E) {
    int e = blockIdx.x * blockDim.x + threadIdx.x;
    if (e < E) {
        int p = atomicAdd(&cursor[dst[e]], 1);
        pos[e] = p;
        srcs[p] = src[e];
    }
}

// ---- weight prep: transposed bf16 weights, extended with el/er projection rows ----
// Layout: rows 0..M-1 = W^T; rows M..M+H-1 = W·al (head h); rows M+H..M+2H-1 = W·ar;
// remaining rows zero.  (For res weights: plain transpose + zero pad.)
__global__ void prep_w_all(const float* __restrict__ W0, const float* __restrict__ W1,
                           const float* __restrict__ rW1, const float* __restrict__ W2,
                           const float* __restrict__ rW2,
                           const float* __restrict__ al0, const float* __restrict__ ar0,
                           const float* __restrict__ al1, const float* __restrict__ ar1,
                           const float* __restrict__ al2, const float* __restrict__ ar2,
                           bf16* __restrict__ W0t, bf16* __restrict__ W1t,
                           bf16* __restrict__ rW1t, bf16* __restrict__ W2t,
                           bf16* __restrict__ rW2t) {
    const float *W, *al, *ar; bf16* Wt; int K, M, rows, H, D;
    switch (blockIdx.y) {
        case 0: W = W0;  Wt = W0t;  K = 256; M = 128; rows = 144; H = 4; D = 32; al = al0; ar = ar0; break;
        case 1: W = W1;  Wt = W1t;  K = 128; M = 128; rows = 144; H = 4; D = 32; al = al1; ar = ar1; break;
        case 2: W = rW1; Wt = rW1t; K = 128; M = 128; rows = 128; H = 0; D = 0;  al = nullptr; ar = nullptr; break;
        case 3: W = W2;  Wt = W2t;  K = 128; M = 47;  rows = 64;  H = 1; D = 47; al = al2; ar = ar2; break;
        default: W = rW2; Wt = rW2t; K = 128; M = 47; rows = 48;  H = 0; D = 0;  al = nullptr; ar = nullptr; break;
    }
    int i = blockIdx.x * 256 + threadIdx.x;
    if (i >= rows * K) return;
    int row = i / K, k = i - row * K;
    float v = 0.f;
    if (row < M) {
        v = W[(long)k * M + row];
    } else if (H > 0 && row < M + 2 * H) {
        int idx = row - M;
        int h = (idx < H) ? idx : idx - H;
        const float* a = (idx < H) ? al : ar;
        float s = 0.f;
        for (int d = 0; d < D; ++d) s += W[(long)k * M + h * D + d] * a[h * D + d];
        v = s;
    }
    Wt[i] = __float2bfloat16(v);
}

// ---- bf16 MFMA GEMM + fused attn projections ----
// C = A[N,K] @ B1t^T -> featb (bf16, cols<M), el (cols M..M+H-1), er (M+H..M+2H-1)
// optional dual: C2 (f32) = A @ B2t^T (res branch, cols<M).
// Block: 64 rows, 4 waves (wave w owns rows w*16..w*16+15).
template <bool A_F32, int NT1, int NT2, int HH>
__global__ __launch_bounds__(256) void gemm_mfma(
    const void* __restrict__ Av, const bf16* __restrict__ B1t,
    const bf16* __restrict__ B2t,
    bf16* __restrict__ C1b, float* __restrict__ el, float* __restrict__ er,
    float* __restrict__ C2, int N, int K, int M) {
    constexpr int LP = 56;  // 32 k + pad: rows 112B (16B-aligned, 2-way alias = free)
    __shared__ bf16 As[64][LP];
    __shared__ bf16 Bs1[NT1 * 16][LP];
    __shared__ bf16 Bs2[(NT2 > 0) ? NT2 * 16 : 1][LP];

    const int tid = threadIdx.x;
    const int lane = tid & 63;
    const int wid = tid >> 6;
    const int row0 = blockIdx.x * 64;
    const int l15 = lane & 15;
    const int kq = lane >> 4;          // k-quarter 0..3

    f32x4 acc1[NT1], acc2[(NT2 > 0) ? NT2 : 1];
    #pragma unroll
    for (int t = 0; t < NT1; ++t) acc1[t] = (f32x4){0.f, 0.f, 0.f, 0.f};
    if constexpr (NT2 > 0) {
        #pragma unroll
        for (int t = 0; t < NT2; ++t) acc2[t] = (f32x4){0.f, 0.f, 0.f, 0.f};
    }

    for (int k0 = 0; k0 < K; k0 += 32) {
        // stage A: 64 rows x 32 k (each thread: 8 contiguous k of one row)
        {
            const int r = tid >> 2, kk = (tid & 3) * 8;
            const int gr = row0 + r;
            if constexpr (A_F32) {
                const float* A = (const float*)Av;
                short tmp[8];
                if (gr < N) {
                    const float4 v0 = *(const float4*)&A[(long)gr * K + k0 + kk];
                    const float4 v1 = *(const float4*)&A[(long)gr * K + k0 + kk + 4];
                    tmp[0] = f2bf(v0.x); tmp[1] = f2bf(v0.y); tmp[2] = f2bf(v0.z); tmp[3] = f2bf(v0.w);
                    tmp[4] = f2bf(v1.x); tmp[5] = f2bf(v1.y); tmp[6] = f2bf(v1.z); tmp[7] = f2bf(v1.w);
                } else {
                    #pragma unroll
                    for (int j = 0; j < 8; ++j) tmp[j] = 0;
                }
                *(frag_ab*)&As[r][kk] = *(const frag_ab*)tmp;
            } else {
                const bf16* A = (const bf16*)Av;
                frag_ab v = {0, 0, 0, 0, 0, 0, 0, 0};
                if (gr < N) v = *(const frag_ab*)&A[(long)gr * K + k0 + kk];
                *(frag_ab*)&As[r][kk] = v;
            }
        }
        // stage B tiles (coalesced rows of transposed weights)
        for (int i = tid; i < NT1 * 64; i += 256) {
            const int c = i >> 2, kk = (i & 3) * 8;
            *(frag_ab*)&Bs1[c][kk] = *(const frag_ab*)&B1t[(long)c * K + k0 + kk];
        }
        if constexpr (NT2 > 0) {
            for (int i = tid; i < NT2 * 64; i += 256) {
                const int c = i >> 2, kk = (i & 3) * 8;
                *(frag_ab*)&Bs2[c][kk] = *(const frag_ab*)&B2t[(long)c * K + k0 + kk];
            }
        }
        __syncthreads();

        const frag_ab a = *(const frag_ab*)&As[wid * 16 + l15][kq * 8];
        #pragma unroll
        for (int t = 0; t < NT1; ++t) {
            const frag_ab b = *(const frag_ab*)&Bs1[t * 16 + l15][kq * 8];
            acc1[t] = __builtin_amdgcn_mfma_f32_16x16x32_bf16(a, b, acc1[t], 0, 0, 0);
        }
        if constexpr (NT2 > 0) {
            #pragma unroll
            for (int t = 0; t < NT2; ++t) {
                const frag_ab b = *(const frag_ab*)&Bs2[t * 16 + l15][kq * 8];
                acc2[t] = __builtin_amdgcn_mfma_f32_16x16x32_bf16(a, b, acc2[t], 0, 0, 0);
            }
        }
        __syncthreads();
    }

    // epilogue: D row = (lane>>4)*4 + reg, col = lane&15
    const int r0 = row0 + wid * 16 + kq * 4;
    #pragma unroll
    for (int t = 0; t < NT1; ++t) {
        const int c = t * 16 + l15;
        #pragma unroll
        for (int reg = 0; reg < 4; ++reg) {
            const int r = r0 + reg;
            if (r >= N) continue;
            const float v = acc1[t][reg];
            if (c < M) {
                C1b[(long)r * M + c] = __float2bfloat16(v);
            } else if (c < M + HH) {
                el[(long)r * HH + (c - M)] = v;
            } else if (c < M + 2 * HH) {
                er[(long)r * HH + (c - M - HH)] = v;
            }
        }
    }
    if constexpr (NT2 > 0) {
        #pragma unroll
        for (int t = 0; t < NT2; ++t) {
            const int c = t * 16 + l15;
            if (c >= M) continue;
            #pragma unroll
            for (int reg = 0; reg < 4; ++reg) {
                const int r = r0 + reg;
                if (r < N) C2[(long)r * M + c] = acc2[t][reg];
            }
        }
    }
}

// ---- edge scores e = leaky_relu(el[src]+er[dst]); dual write: edge order + CSR order ----
template <int H>
__global__ void edge_e(const float* __restrict__ el, const float* __restrict__ er,
                       const int* __restrict__ src, const int* __restrict__ dst,
                       const int* __restrict__ pos,
                       float* __restrict__ e_out, float* __restrict__ es, int E) {
    int e = blockIdx.x * blockDim.x + threadIdx.x;
    if (e >= E) return;
    int s = src[e], d = dst[e], p = pos[e];
    if constexpr (H == 4) {
        float4 a = *reinterpret_cast<const float4*>(el + s * 4);
        float4 b = *reinterpret_cast<const float4*>(er + d * 4);
        float4 v;
        v.x = a.x + b.x; v.y = a.y + b.y; v.z = a.z + b.z; v.w = a.w + b.w;
        v.x = (v.x >= 0.f) ? v.x : 0.2f * v.x;
        v.y = (v.y >= 0.f) ? v.y : 0.2f * v.y;
        v.z = (v.z >= 0.f) ? v.z : 0.2f * v.z;
        v.w = (v.w >= 0.f) ? v.w : 0.2f * v.w;
        *reinterpret_cast<float4*>(e_out + e * 4) = v;
        *reinterpret_cast<float4*>(es + p * 4) = v;
    } else {
        float v = el[s] + er[d];
        v = (v >= 0.f) ? v : 0.2f * v;
        e_out[e] = v;
        es[p] = v;
    }
}

// ---- node-centric softmax + aggregation, one wave/node, H=4 D=32 (HD=128) ----
// Phase 1: max (lane-strided).  Phase 2: t=exp(e-m), s+=t, write t back to es
// (lane-strided; exp computed once per edge per head, NOT per lane).
// Phase 3: pure weighted gather (broadcast 4B weight + 2 FMA per lane per edge).
// Normalization folded into the epilogue (acc * 1/s).
template <int NELU, bool HAS_RES>
__global__ __launch_bounds__(256) void node_agg4(
    const bf16* __restrict__ featb, float4* __restrict__ es4,
    const int* __restrict__ offs, const int* __restrict__ srcs,
    const float* __restrict__ res, bf16* __restrict__ out, int n) {
    const int node = (int)((blockIdx.x * blockDim.x + threadIdx.x) >> 6);
    const int lane = threadIdx.x & 63;
    if (node >= n) return;
    const int beg = offs[node], end = offs[node + 1];

    // phase 1: per-head max (coalesced)
    float4 m4 = make_float4(-INFINITY, -INFINITY, -INFINITY, -INFINITY);
    for (int i = beg + lane; i < end; i += 64) {
        float4 v = es4[i];
        m4.x = fmaxf(m4.x, v.x); m4.y = fmaxf(m4.y, v.y);
        m4.z = fmaxf(m4.z, v.z); m4.w = fmaxf(m4.w, v.w);
    }
    #pragma unroll
    for (int off = 32; off > 0; off >>= 1) {
        m4.x = fmaxf(m4.x, __shfl_xor(m4.x, off));
        m4.y = fmaxf(m4.y, __shfl_xor(m4.y, off));
        m4.z = fmaxf(m4.z, __shfl_xor(m4.z, off));
        m4.w = fmaxf(m4.w, __shfl_xor(m4.w, off));
    }
    // phase 2: t = exp(e-m); sum; write t back in place
    float4 s4 = make_float4(0.f, 0.f, 0.f, 0.f);
    for (int i = beg + lane; i < end; i += 64) {
        float4 v = es4[i];
        float4 t;
        t.x = __expf(v.x - m4.x); t.y = __expf(v.y - m4.y);
        t.z = __expf(v.z - m4.z); t.w = __expf(v.w - m4.w);
        s4.x += t.x; s4.y += t.y; s4.z += t.z; s4.w += t.w;
        es4[i] = t;
    }
    #pragma unroll
    for (int off = 32; off > 0; off >>= 1) {
        s4.x += __shfl_xor(s4.x, off);
        s4.y += __shfl_xor(s4.y, off);
        s4.z += __shfl_xor(s4.z, off);
        s4.w += __shfl_xor(s4.w, off);
    }

    const int fi = lane * 2;           // two consecutive features, same head
    const int h = lane >> 4;           // fi / 32
    const float sh = (h == 0) ? s4.x : (h == 1) ? s4.y : (h == 2) ? s4.z : s4.w;
    const float inv = 1.f / fmaxf(sh, 1e-9f);

    // phase 3: weighted gather — no exp, broadcast weight + 2 FMA per edge
    const float* esf = (const float*)es4;
    float acc0 = 0.f, acc1 = 0.f;
    int i = beg;
    for (; i + 4 <= end; i += 4) {
        const int sn0 = srcs[i], sn1 = srcs[i + 1], sn2 = srcs[i + 2], sn3 = srcs[i + 3];
        const float w0 = esf[(i + 0) * 4 + h];
        const float w1 = esf[(i + 1) * 4 + h];
        const float w2 = esf[(i + 2) * 4 + h];
        const float w3 = esf[(i + 3) * 4 + h];
        const __hip_bfloat162 f0 = *reinterpret_cast<const __hip_bfloat162*>(featb + (long)sn0 * 128 + fi);
        const __hip_bfloat162 f1 = *reinterpret_cast<const __hip_bfloat162*>(featb + (long)sn1 * 128 + fi);
        const __hip_bfloat162 f2 = *reinterpret_cast<const __hip_bfloat162*>(featb + (long)sn2 * 128 + fi);
        const __hip_bfloat162 f3 = *reinterpret_cast<const __hip_bfloat162*>(featb + (long)sn3 * 128 + fi);
        acc0 += w0 * __bfloat162float(f0.x); acc1 += w0 * __bfloat162float(f0.y);
        acc0 += w1 * __bfloat162float(f1.x); acc1 += w1 * __bfloat162float(f1.y);
        acc0 += w2 * __bfloat162float(f2.x); acc1 += w2 * __bfloat162float(f2.y);
        acc0 += w3 * __bfloat162float(f3.x); acc1 += w3 * __bfloat162float(f3.y);
    }
    for (; i < end; ++i) {
        const int sn = srcs[i];
        const float w = esf[i * 4 + h];
        const __hip_bfloat162 f2 = *reinterpret_cast<const __hip_bfloat162*>(featb + (long)sn * 128 + fi);
        acc0 += w * __bfloat162float(f2.x);
        acc1 += w * __bfloat162float(f2.y);
    }

    float v0 = acc0 * inv, v1 = acc1 * inv;
    if constexpr (HAS_RES) {
        const float2 rr = *reinterpret_cast<const float2*>(res + (long)node * 128 + fi);
        v0 += rr.x; v1 += rr.y;
    }
    #pragma unroll
    for (int t = 0; t < NELU; ++t) {
        v0 = (v0 > 0.f) ? v0 : expm1f(v0);
        v1 = (v1 > 0.f) ? v1 : expm1f(v1);
    }
    __hip_bfloat162 o;
    o.x = __float2bfloat16(v0);
    o.y = __float2bfloat16(v1);
    *reinterpret_cast<__hip_bfloat162*>(out + (long)node * 128 + fi) = o;
}

// ---- node-centric softmax + aggregation, H=1, HD=47 (final layer) ----
__global__ __launch_bounds__(256) void node_agg1(
    const bf16* __restrict__ featb, float* __restrict__ es1,
    const int* __restrict__ offs, const int* __restrict__ srcs,
    const float* __restrict__ res, float* __restrict__ out, int n) {
    const int node = (int)((blockIdx.x * blockDim.x + threadIdx.x) >> 6);
    const int lane = threadIdx.x & 63;
    if (node >= n) return;
    const int beg = offs[node], end = offs[node + 1];

    float m = -INFINITY;
    for (int i = beg + lane; i < end; i += 64) m = fmaxf(m, es1[i]);
    #pragma unroll
    for (int off = 32; off > 0; off >>= 1) m = fmaxf(m, __shfl_xor(m, off));
    float s = 0.f;
    for (int i = beg + lane; i < end; i += 64) {
        const float t = __expf(es1[i] - m);
        s += t;
        es1[i] = t;
    }
    #pragma unroll
    for (int off = 32; off > 0; off >>= 1) s += __shfl_xor(s, off);
    const float inv = 1.f / fmaxf(s, 1e-9f);

    const bool active = lane < NC;
    float acc = 0.f;
    int i = beg;
    for (; i + 4 <= end; i += 4) {
        const int sn0 = srcs[i], sn1 = srcs[i + 1], sn2 = srcs[i + 2], sn3 = srcs[i + 3];
        const float w0 = es1[i + 0], w1 = es1[i + 1];
        const float w2 = es1[i + 2], w3 = es1[i + 3];
        if (active) {
            acc += w0 * __bfloat162float(featb[(long)sn0 * NC + lane]);
            acc += w1 * __bfloat162float(featb[(long)sn1 * NC + lane]);
            acc += w2 * __bfloat162float(featb[(long)sn2 * NC + lane]);
            acc += w3 * __bfloat162float(featb[(long)sn3 * NC + lane]);
        }
    }
    for (; i < end; ++i) {
        const float w = es1[i];
        if (active) acc += w * __bfloat162float(featb[(long)srcs[i] * NC + lane]);
    }
    if (active) {
        out[(long)node * NC + lane] = acc * inv + res[(long)node * NC + lane];
    }
}

extern "C" void kernel_launch(void* const* d_in, const int* in_sizes, int n_in,
                              void* d_out, int out_size, void* d_ws, size_t ws_size,
                              hipStream_t stream) {
    const float* x     = (const float*)d_in[0];
    const float* W0    = (const float*)d_in[1];
    const float* al0   = (const float*)d_in[2];
    const float* ar0   = (const float*)d_in[3];
    const float* W1    = (const float*)d_in[4];
    const float* resW1 = (const float*)d_in[5];
    const float* al1   = (const float*)d_in[6];
    const float* ar1   = (const float*)d_in[7];
    const float* W2    = (const float*)d_in[8];
    const float* resW2 = (const float*)d_in[9];
    const float* al2   = (const float*)d_in[10];
    const float* ar2   = (const float*)d_in[11];
    const int*   src   = (const int*)d_in[12];
    const int*   dst   = (const int*)d_in[13];

    float* out    = (float*)d_out;
    float* logits = out;                 // [N, 47]
    float* e0     = out + (long)NN * NC; // [E, 4]
    float* e1     = e0 + (long)NE * NH;  // [E, 4]
    float* e2     = e1 + (long)NE * NH;  // [E, 1]

    char* p = (char*)d_ws;
    int* offs   = (int*)p; p += align256(sizeof(int) * (NN + 1));
    int* cursor = (int*)p; p += align256(sizeof(int) * NN);
    int* pos    = (int*)p; p += align256(sizeof(int) * NE);
    int* srcs   = (int*)p; p += align256(sizeof(int) * NE);
    float* el   = (float*)p; p += align256(sizeof(float) * NN * NH);
    float* er   = (float*)p; p += align256(sizeof(float) * NN * NH);
    float* es   = (float*)p; p += align256(sizeof(float) * (long)NE * NH);
    float* resb = (float*)p; p += align256(sizeof(float) * (long)NN * 128);
    bf16* featb = (bf16*)p; p += align256(sizeof(bf16) * (long)NN * 128);
    bf16* hb    = (bf16*)p; p += align256(sizeof(bf16) * (long)NN * 128);
    bf16* W0t   = (bf16*)p; p += align256(sizeof(bf16) * 144 * 256);
    bf16* W1t   = (bf16*)p; p += align256(sizeof(bf16) * 144 * 128);
    bf16* rW1t  = (bf16*)p; p += align256(sizeof(bf16) * 128 * 128);
    bf16* W2t   = (bf16*)p; p += align256(sizeof(bf16) * 64 * 128);
    bf16* rW2t  = (bf16*)p; p += align256(sizeof(bf16) * 48 * 128);

    // ---- weight prep (transpose + fused attn-projection columns) ----
    prep_w_all<<<dim3(144, 5), 256, 0, stream>>>(W0, W1, resW1, W2, resW2,
                                                 al0, ar0, al1, ar1, al2, ar2,
                                                 W0t, W1t, rW1t, W2t, rW2t);

    // ---- CSR by dst (rebuilt every call; deterministic structure) ----
    hipMemsetAsync(cursor, 0, sizeof(int) * NN, stream);
    count_k<<<(NE + 255) / 256, 256, 0, stream>>>(dst, cursor, NE);
    scan_k<<<1, 1024, 0, stream>>>(cursor, offs, cursor, NN);
    fill_k<<<(NE + 255) / 256, 256, 0, stream>>>(dst, src, cursor, pos, srcs, NE);

    const int gemmBlocks = (NN + 63) / 64;   // 469
    const int edgeBlocks = (NE + 255) / 256;
    const int nodeBlocks = NN / 4;           // one wave per node, 4 waves/block

    // ---- layer 0: x @ [W0|wl0|wr0] -> featb bf16 + el + er ----
    gemm_mfma<true, 9, 0, NH><<<gemmBlocks, 256, 0, stream>>>(
        x, W0t, nullptr, featb, el, er, nullptr, NN, FIN, 128);
    edge_e<NH><<<edgeBlocks, 256, 0, stream>>>(el, er, src, dst, pos, e0, es, NE);
    node_agg4<1, false><<<nodeBlocks, 256, 0, stream>>>(
        featb, (float4*)es, offs, srcs, nullptr, hb, NN);

    // ---- layer 1: hb @ [W1|wl1|wr1] + hb @ resW1 -> featb/el/er + resb ----
    gemm_mfma<false, 9, 8, NH><<<gemmBlocks, 256, 0, stream>>>(
        hb, W1t, rW1t, featb, el, er, resb, NN, 128, 128);
    edge_e<NH><<<edgeBlocks, 256, 0, stream>>>(el, er, src, dst, pos, e1, es, NE);
    node_agg4<2, true><<<nodeBlocks, 256, 0, stream>>>(
        featb, (float4*)es, offs, srcs, resb, hb, NN);

    // ---- final layer: hb @ [W2|wl2|wr2] + hb @ resW2 (M=47) ----
    gemm_mfma<false, 4, 3, 1><<<gemmBlocks, 256, 0, stream>>>(
        hb, W2t, rW2t, featb, el, er, resb, NN, 128, NC);
    edge_e<1><<<edgeBlocks, 256, 0, stream>>>(el, er, src, dst, pos, e2, es, NE);
    node_agg1<<<nodeBlocks, 256, 0, stream>>>(
        featb, es, offs, srcs, resb, logits, NN);
}

// Round 8
// 239.561 us; speedup vs baseline: 1.1794x; 1.0732x over previous
//
#include <hip/hip_runtime.h>
#include <hip/hip_bf16.h>
#include <math.h>

// Problem constants
#define NN 30000
#define NE 480000
#define FIN 256
#define DH 32
#define NH 4
#define NC 47

typedef __attribute__((ext_vector_type(8))) short frag_ab;  // 8 bf16 (4 VGPR)
typedef __attribute__((ext_vector_type(4))) float f32x4;    // MFMA 16x16 accum
typedef __hip_bfloat16 bf16;

static inline size_t align256(size_t x) { return (x + 255) & ~(size_t)255; }

__device__ __forceinline__ short f2bf(float f) {
    union { float f; unsigned u; } c; c.f = f;
    unsigned r = (c.u + 0x7FFFu + ((c.u >> 16) & 1u)) >> 16;  // RNE
    return (short)r;
}
__device__ __forceinline__ float b2f(unsigned short u) {
    union { unsigned u; float f; } c; c.u = (unsigned)u << 16; return c.f;
}
// exp(leaky_relu(v)) — no max subtraction (scores are O(10), far from f32 overflow)
__device__ __forceinline__ float expw(float v) {
    return __expf((v >= 0.f) ? v : 0.2f * v);
}

// ---------------- CSR build ----------------
__global__ void count_k(const int* __restrict__ dst, int* __restrict__ cnt, int E) {
    int e = blockIdx.x * blockDim.x + threadIdx.x;
    if (e < E) atomicAdd(&cnt[dst[e]], 1);
}

// exclusive scan; writes offs[0..n] AND cursor[0..n-1] (fill cursors)
__global__ __launch_bounds__(1024) void scan_k(const int* __restrict__ cnt,
                                               int* __restrict__ offs,
                                               int* __restrict__ cursor, int n) {
    __shared__ int warp_sums[16];
    __shared__ int carry_s;
    const int lane = threadIdx.x & 63;
    const int wid = threadIdx.x >> 6;
    if (threadIdx.x == 0) carry_s = 0;
    __syncthreads();
    for (int base = 0; base < n; base += 1024) {
        int i = base + threadIdx.x;
        int v = (i < n) ? cnt[i] : 0;
        int x = v;
        #pragma unroll
        for (int off = 1; off < 64; off <<= 1) {
            int y = __shfl_up(x, off);
            if (lane >= off) x += y;
        }
        if (lane == 63) warp_sums[wid] = x;
        __syncthreads();
        if (wid == 0) {
            int ws = (lane < 16) ? warp_sums[lane] : 0;
            #pragma unroll
            for (int off = 1; off < 16; off <<= 1) {
                int y = __shfl_up(ws, off);
                if (lane >= off) ws += y;
            }
            if (lane < 16) warp_sums[lane] = ws;
        }
        __syncthreads();
        int wbase = (wid > 0) ? warp_sums[wid - 1] : 0;
        int incl = x + wbase + carry_s;
        if (i < n) {
            offs[i] = incl - v;  // exclusive
            cursor[i] = incl - v;
        }
        __syncthreads();
        if (threadIdx.x == 1023) carry_s = incl;
        __syncthreads();
    }
    if (threadIdx.x == 0) offs[n] = carry_s;
}

// srcs[slot] = src id, in CSR-by-dst order
__global__ void fill_k(const int* __restrict__ dst, const int* __restrict__ src,
                       int* __restrict__ cursor, int* __restrict__ srcs, int E) {
    int e = blockIdx.x * blockDim.x + threadIdx.x;
    if (e < E) {
        int p = atomicAdd(&cursor[dst[e]], 1);
        srcs[p] = src[e];
    }
}

// ---- weight prep (+ cursor zeroing in y==5): transposed bf16 weights with
// fused el/er projection rows. Rows 0..M-1 = W^T; M..M+H-1 = W·al; M+H..M+2H-1 = W·ar.
__global__ void prep_w_all(const float* __restrict__ W0, const float* __restrict__ W1,
                           const float* __restrict__ rW1, const float* __restrict__ W2,
                           const float* __restrict__ rW2,
                           const float* __restrict__ al0, const float* __restrict__ ar0,
                           const float* __restrict__ al1, const float* __restrict__ ar1,
                           const float* __restrict__ al2, const float* __restrict__ ar2,
                           bf16* __restrict__ W0t, bf16* __restrict__ W1t,
                           bf16* __restrict__ rW1t, bf16* __restrict__ W2t,
                           bf16* __restrict__ rW2t, int* __restrict__ cursor) {
    if (blockIdx.y == 5) {
        int i = blockIdx.x * 256 + threadIdx.x;
        if (i < NN) cursor[i] = 0;
        return;
    }
    const float *W, *al, *ar; bf16* Wt; int K, M, rows, H, D;
    switch (blockIdx.y) {
        case 0: W = W0;  Wt = W0t;  K = 256; M = 128; rows = 144; H = 4; D = 32; al = al0; ar = ar0; break;
        case 1: W = W1;  Wt = W1t;  K = 128; M = 128; rows = 144; H = 4; D = 32; al = al1; ar = ar1; break;
        case 2: W = rW1; Wt = rW1t; K = 128; M = 128; rows = 128; H = 0; D = 0;  al = nullptr; ar = nullptr; break;
        case 3: W = W2;  Wt = W2t;  K = 128; M = 47;  rows = 64;  H = 1; D = 47; al = al2; ar = ar2; break;
        default: W = rW2; Wt = rW2t; K = 128; M = 47; rows = 48;  H = 0; D = 0;  al = nullptr; ar = nullptr; break;
    }
    int i = blockIdx.x * 256 + threadIdx.x;
    if (i >= rows * K) return;
    int row = i / K, k = i - row * K;
    float v = 0.f;
    if (row < M) {
        v = W[(long)k * M + row];
    } else if (H > 0 && row < M + 2 * H) {
        int idx = row - M;
        int h = (idx < H) ? idx : idx - H;
        const float* a = (idx < H) ? al : ar;
        float s = 0.f;
        for (int d = 0; d < D; ++d) s += W[(long)k * M + h * D + d] * a[h * D + d];
        v = s;
    }
    Wt[i] = __float2bfloat16(v);
}

// ---- bf16 MFMA GEMM + fused attn projections ----
template <bool A_F32, int NT1, int NT2, int HH>
__global__ __launch_bounds__(256) void gemm_mfma(
    const void* __restrict__ Av, const bf16* __restrict__ B1t,
    const bf16* __restrict__ B2t,
    bf16* __restrict__ C1b, float* __restrict__ el, float* __restrict__ er,
    float* __restrict__ C2, int N, int K, int M) {
    constexpr int LP = 56;  // 32 k + pad: rows 112B (16B-aligned, 2-way alias = free)
    __shared__ bf16 As[64][LP];
    __shared__ bf16 Bs1[NT1 * 16][LP];
    __shared__ bf16 Bs2[(NT2 > 0) ? NT2 * 16 : 1][LP];

    const int tid = threadIdx.x;
    const int lane = tid & 63;
    const int wid = tid >> 6;
    const int row0 = blockIdx.x * 64;
    const int l15 = lane & 15;
    const int kq = lane >> 4;          // k-quarter 0..3

    f32x4 acc1[NT1], acc2[(NT2 > 0) ? NT2 : 1];
    #pragma unroll
    for (int t = 0; t < NT1; ++t) acc1[t] = (f32x4){0.f, 0.f, 0.f, 0.f};
    if constexpr (NT2 > 0) {
        #pragma unroll
        for (int t = 0; t < NT2; ++t) acc2[t] = (f32x4){0.f, 0.f, 0.f, 0.f};
    }

    for (int k0 = 0; k0 < K; k0 += 32) {
        {
            const int r = tid >> 2, kk = (tid & 3) * 8;
            const int gr = row0 + r;
            if constexpr (A_F32) {
                const float* A = (const float*)Av;
                short tmp[8];
                if (gr < N) {
                    const float4 v0 = *(const float4*)&A[(long)gr * K + k0 + kk];
                    const float4 v1 = *(const float4*)&A[(long)gr * K + k0 + kk + 4];
                    tmp[0] = f2bf(v0.x); tmp[1] = f2bf(v0.y); tmp[2] = f2bf(v0.z); tmp[3] = f2bf(v0.w);
                    tmp[4] = f2bf(v1.x); tmp[5] = f2bf(v1.y); tmp[6] = f2bf(v1.z); tmp[7] = f2bf(v1.w);
                } else {
                    #pragma unroll
                    for (int j = 0; j < 8; ++j) tmp[j] = 0;
                }
                *(frag_ab*)&As[r][kk] = *(const frag_ab*)tmp;
            } else {
                const bf16* A = (const bf16*)Av;
                frag_ab v = {0, 0, 0, 0, 0, 0, 0, 0};
                if (gr < N) v = *(const frag_ab*)&A[(long)gr * K + k0 + kk];
                *(frag_ab*)&As[r][kk] = v;
            }
        }
        for (int i = tid; i < NT1 * 64; i += 256) {
            const int c = i >> 2, kk = (i & 3) * 8;
            *(frag_ab*)&Bs1[c][kk] = *(const frag_ab*)&B1t[(long)c * K + k0 + kk];
        }
        if constexpr (NT2 > 0) {
            for (int i = tid; i < NT2 * 64; i += 256) {
                const int c = i >> 2, kk = (i & 3) * 8;
                *(frag_ab*)&Bs2[c][kk] = *(const frag_ab*)&B2t[(long)c * K + k0 + kk];
            }
        }
        __syncthreads();

        const frag_ab a = *(const frag_ab*)&As[wid * 16 + l15][kq * 8];
        #pragma unroll
        for (int t = 0; t < NT1; ++t) {
            const frag_ab b = *(const frag_ab*)&Bs1[t * 16 + l15][kq * 8];
            acc1[t] = __builtin_amdgcn_mfma_f32_16x16x32_bf16(a, b, acc1[t], 0, 0, 0);
        }
        if constexpr (NT2 > 0) {
            #pragma unroll
            for (int t = 0; t < NT2; ++t) {
                const frag_ab b = *(const frag_ab*)&Bs2[t * 16 + l15][kq * 8];
                acc2[t] = __builtin_amdgcn_mfma_f32_16x16x32_bf16(a, b, acc2[t], 0, 0, 0);
            }
        }
        __syncthreads();
    }

    const int r0 = row0 + wid * 16 + kq * 4;
    #pragma unroll
    for (int t = 0; t < NT1; ++t) {
        const int c = t * 16 + l15;
        #pragma unroll
        for (int reg = 0; reg < 4; ++reg) {
            const int r = r0 + reg;
            if (r >= N) continue;
            const float v = acc1[t][reg];
            if (c < M) {
                C1b[(long)r * M + c] = __float2bfloat16(v);
            } else if (c < M + HH) {
                el[(long)r * HH + (c - M)] = v;
            } else if (c < M + 2 * HH) {
                er[(long)r * HH + (c - M - HH)] = v;
            }
        }
    }
    if constexpr (NT2 > 0) {
        #pragma unroll
        for (int t = 0; t < NT2; ++t) {
            const int c = t * 16 + l15;
            if (c >= M) continue;
            #pragma unroll
            for (int reg = 0; reg < 4; ++reg) {
                const int r = r0 + reg;
                if (r < N) C2[(long)r * M + c] = acc2[t][reg];
            }
        }
    }
}

// ---- edge scores e = leaky_relu(el[src]+er[dst]) -> e_out (coalesced, edge order) ----
template <int H>
__global__ void edge_e(const float* __restrict__ el, const float* __restrict__ er,
                       const int* __restrict__ src, const int* __restrict__ dst,
                       float* __restrict__ e_out, int E) {
    int e = blockIdx.x * blockDim.x + threadIdx.x;
    if (e >= E) return;
    int s = src[e], d = dst[e];
    if constexpr (H == 4) {
        float4 a = *reinterpret_cast<const float4*>(el + s * 4);
        float4 b = *reinterpret_cast<const float4*>(er + d * 4);
        float4 v;
        v.x = a.x + b.x; v.y = a.y + b.y; v.z = a.z + b.z; v.w = a.w + b.w;
        v.x = (v.x >= 0.f) ? v.x : 0.2f * v.x;
        v.y = (v.y >= 0.f) ? v.y : 0.2f * v.y;
        v.z = (v.z >= 0.f) ? v.z : 0.2f * v.z;
        v.w = (v.w >= 0.f) ? v.w : 0.2f * v.w;
        *reinterpret_cast<float4*>(e_out + e * 4) = v;
    } else {
        float v = el[s] + er[d];
        e_out[e] = (v >= 0.f) ? v : 0.2f * v;
    }
}

// ---- node softmax + aggregation, one wave/node, H=4 D=32 (HD=128) ----
// Phase A (lane-strided): t = exp(lrelu(el[src]+er[node])) per edge (once!),
//   s += t, write t to es coalesced. No max pass (scores O(10) << 88).
// Phase B (half-wave per edge): 32 lanes x ushort4 row gather, 2 edges/iter.
// NOTE: grid is exactly NN/4 blocks x 4 waves -> every wave has a valid node
// (required: __syncthreads below must be reached by all).
template <int NELU, bool HAS_RES>
__global__ __launch_bounds__(256) void node_agg4(
    const bf16* __restrict__ featb, const float4* __restrict__ el4,
    const float4* __restrict__ er4, float4* __restrict__ es4,
    const int* __restrict__ offs, const int* __restrict__ srcs,
    const float* __restrict__ res, bf16* __restrict__ out) {
    const int node = (int)((blockIdx.x * blockDim.x + threadIdx.x) >> 6);
    const int lane = threadIdx.x & 63;
    const int beg = offs[node], end = offs[node + 1];
    const float4 ern = er4[node];   // wave-uniform

    // phase A
    float4 s4 = make_float4(0.f, 0.f, 0.f, 0.f);
    for (int i = beg + lane; i < end; i += 64) {
        const float4 elv = el4[srcs[i]];
        float4 t;
        t.x = expw(elv.x + ern.x); t.y = expw(elv.y + ern.y);
        t.z = expw(elv.z + ern.z); t.w = expw(elv.w + ern.w);
        s4.x += t.x; s4.y += t.y; s4.z += t.z; s4.w += t.w;
        es4[i] = t;
    }
    #pragma unroll
    for (int off = 32; off > 0; off >>= 1) {
        s4.x += __shfl_xor(s4.x, off);
        s4.y += __shfl_xor(s4.y, off);
        s4.z += __shfl_xor(s4.z, off);
        s4.w += __shfl_xor(s4.w, off);
    }
    __syncthreads();   // make phase-A es stores visible to all lanes' reads

    // phase B: two edges per iteration (half-wave each)
    const int half = lane >> 5;
    const int l31 = lane & 31;
    const int fi = l31 * 4;           // 4 consecutive features
    const int h = l31 >> 3;           // fi / 32
    const float sh = (h == 0) ? s4.x : (h == 1) ? s4.y : (h == 2) ? s4.z : s4.w;
    const float inv = 1.f / fmaxf(sh, 1e-9f);
    const float* esf = (const float*)es4;

    float a0 = 0.f, a1 = 0.f, a2 = 0.f, a3 = 0.f;
    int i = beg + half;
    for (; i + 2 < end; i += 4) {
        const int snA = srcs[i], snB = srcs[i + 2];
        const float wA = esf[i * 4 + h];
        const float wB = esf[(i + 2) * 4 + h];
        const ushort4 fA = *(const ushort4*)(featb + (long)snA * 128 + fi);
        const ushort4 fB = *(const ushort4*)(featb + (long)snB * 128 + fi);
        a0 += wA * b2f(fA.x) + wB * b2f(fB.x);
        a1 += wA * b2f(fA.y) + wB * b2f(fB.y);
        a2 += wA * b2f(fA.z) + wB * b2f(fB.z);
        a3 += wA * b2f(fA.w) + wB * b2f(fB.w);
    }
    for (; i < end; i += 2) {
        const int sn = srcs[i];
        const float w = esf[i * 4 + h];
        const ushort4 f = *(const ushort4*)(featb + (long)sn * 128 + fi);
        a0 += w * b2f(f.x); a1 += w * b2f(f.y);
        a2 += w * b2f(f.z); a3 += w * b2f(f.w);
    }
    a0 += __shfl_xor(a0, 32);
    a1 += __shfl_xor(a1, 32);
    a2 += __shfl_xor(a2, 32);
    a3 += __shfl_xor(a3, 32);

    if (lane < 32) {
        float v0 = a0 * inv, v1 = a1 * inv, v2 = a2 * inv, v3 = a3 * inv;
        if constexpr (HAS_RES) {
            const float4 rr = *(const float4*)(res + (long)node * 128 + fi);
            v0 += rr.x; v1 += rr.y; v2 += rr.z; v3 += rr.w;
        }
        #pragma unroll
        for (int t = 0; t < NELU; ++t) {
            v0 = (v0 > 0.f) ? v0 : expm1f(v0);
            v1 = (v1 > 0.f) ? v1 : expm1f(v1);
            v2 = (v2 > 0.f) ? v2 : expm1f(v2);
            v3 = (v3 > 0.f) ? v3 : expm1f(v3);
        }
        ushort4 o;
        o.x = (unsigned short)f2bf(v0); o.y = (unsigned short)f2bf(v1);
        o.z = (unsigned short)f2bf(v2); o.w = (unsigned short)f2bf(v3);
        *(ushort4*)(out + (long)node * 128 + fi) = o;
    }
}

// ---- node softmax + aggregation, H=1, HD=47 (final layer) ----
__global__ __launch_bounds__(256) void node_agg1(
    const bf16* __restrict__ featb, const float* __restrict__ el1,
    const float* __restrict__ er1, float* __restrict__ es1,
    const int* __restrict__ offs, const int* __restrict__ srcs,
    const float* __restrict__ res, float* __restrict__ out) {
    const int node = (int)((blockIdx.x * blockDim.x + threadIdx.x) >> 6);
    const int lane = threadIdx.x & 63;
    const int beg = offs[node], end = offs[node + 1];
    const float ern = er1[node];

    float s = 0.f;
    for (int i = beg + lane; i < end; i += 64) {
        const float t = expw(el1[srcs[i]] + ern);
        s += t;
        es1[i] = t;
    }
    #pragma unroll
    for (int off = 32; off > 0; off >>= 1) s += __shfl_xor(s, off);
    const float inv = 1.f / fmaxf(s, 1e-9f);
    __syncthreads();   // es1 visibility across lanes

    const bool active = lane < NC;
    float acc = 0.f;
    int i = beg;
    for (; i + 4 <= end; i += 4) {
        const int sn0 = srcs[i], sn1 = srcs[i + 1], sn2 = srcs[i + 2], sn3 = srcs[i + 3];
        const float w0 = es1[i + 0], w1 = es1[i + 1];
        const float w2 = es1[i + 2], w3 = es1[i + 3];
        if (active) {
            acc += w0 * __bfloat162float(featb[(long)sn0 * NC + lane]);
            acc += w1 * __bfloat162float(featb[(long)sn1 * NC + lane]);
            acc += w2 * __bfloat162float(featb[(long)sn2 * NC + lane]);
            acc += w3 * __bfloat162float(featb[(long)sn3 * NC + lane]);
        }
    }
    for (; i < end; ++i) {
        const float w = es1[i];
        if (active) acc += w * __bfloat162float(featb[(long)srcs[i] * NC + lane]);
    }
    if (active) {
        out[(long)node * NC + lane] = acc * inv + res[(long)node * NC + lane];
    }
}

extern "C" void kernel_launch(void* const* d_in, const int* in_sizes, int n_in,
                              void* d_out, int out_size, void* d_ws, size_t ws_size,
                              hipStream_t stream) {
    const float* x     = (const float*)d_in[0];
    const float* W0    = (const float*)d_in[1];
    const float* al0   = (const float*)d_in[2];
    const float* ar0   = (const float*)d_in[3];
    const float* W1    = (const float*)d_in[4];
    const float* resW1 = (const float*)d_in[5];
    const float* al1   = (const float*)d_in[6];
    const float* ar1   = (const float*)d_in[7];
    const float* W2    = (const float*)d_in[8];
    const float* resW2 = (const float*)d_in[9];
    const float* al2   = (const float*)d_in[10];
    const float* ar2   = (const float*)d_in[11];
    const int*   src   = (const int*)d_in[12];
    const int*   dst   = (const int*)d_in[13];

    float* out    = (float*)d_out;
    float* logits = out;                 // [N, 47]
    float* e0     = out + (long)NN * NC; // [E, 4]
    float* e1     = e0 + (long)NE * NH;  // [E, 4]
    float* e2     = e1 + (long)NE * NH;  // [E, 1]

    char* p = (char*)d_ws;
    int* offs   = (int*)p; p += align256(sizeof(int) * (NN + 1));
    int* cursor = (int*)p; p += align256(sizeof(int) * NN);
    int* srcs   = (int*)p; p += align256(sizeof(int) * NE);
    float* el   = (float*)p; p += align256(sizeof(float) * NN * NH);
    float* er   = (float*)p; p += align256(sizeof(float) * NN * NH);
    float* es   = (float*)p; p += align256(sizeof(float) * (long)NE * NH);
    float* resb = (float*)p; p += align256(sizeof(float) * (long)NN * 128);
    bf16* featb = (bf16*)p; p += align256(sizeof(bf16) * (long)NN * 128);
    bf16* hb    = (bf16*)p; p += align256(sizeof(bf16) * (long)NN * 128);
    bf16* W0t   = (bf16*)p; p += align256(sizeof(bf16) * 144 * 256);
    bf16* W1t   = (bf16*)p; p += align256(sizeof(bf16) * 144 * 128);
    bf16* rW1t  = (bf16*)p; p += align256(sizeof(bf16) * 128 * 128);
    bf16* W2t   = (bf16*)p; p += align256(sizeof(bf16) * 64 * 128);
    bf16* rW2t  = (bf16*)p; p += align256(sizeof(bf16) * 48 * 128);

    // ---- weight prep + cursor zero (y==5) ----
    prep_w_all<<<dim3(144, 6), 256, 0, stream>>>(W0, W1, resW1, W2, resW2,
                                                 al0, ar0, al1, ar1, al2, ar2,
                                                 W0t, W1t, rW1t, W2t, rW2t, cursor);

    // ---- CSR by dst (rebuilt every call; deterministic structure) ----
    count_k<<<(NE + 255) / 256, 256, 0, stream>>>(dst, cursor, NE);
    scan_k<<<1, 1024, 0, stream>>>(cursor, offs, cursor, NN);
    fill_k<<<(NE + 255) / 256, 256, 0, stream>>>(dst, src, cursor, srcs, NE);

    const int gemmBlocks = (NN + 63) / 64;   // 469
    const int edgeBlocks = (NE + 255) / 256;
    const int nodeBlocks = NN / 4;           // exact: 7500 blocks x 4 waves

    // ---- layer 0: x @ [W0|wl0|wr0] -> featb bf16 + el + er ----
    gemm_mfma<true, 9, 0, NH><<<gemmBlocks, 256, 0, stream>>>(
        x, W0t, nullptr, featb, el, er, nullptr, NN, FIN, 128);
    edge_e<NH><<<edgeBlocks, 256, 0, stream>>>(el, er, src, dst, e0, NE);
    node_agg4<1, false><<<nodeBlocks, 256, 0, stream>>>(
        featb, (const float4*)el, (const float4*)er, (float4*)es, offs, srcs, nullptr, hb);

    // ---- layer 1: hb @ [W1|wl1|wr1] + hb @ resW1 -> featb/el/er + resb ----
    gemm_mfma<false, 9, 8, NH><<<gemmBlocks, 256, 0, stream>>>(
        hb, W1t, rW1t, featb, el, er, resb, NN, 128, 128);
    edge_e<NH><<<edgeBlocks, 256, 0, stream>>>(el, er, src, dst, e1, NE);
    node_agg4<2, true><<<nodeBlocks, 256, 0, stream>>>(
        featb, (const float4*)el, (const float4*)er, (float4*)es, offs, srcs, resb, hb);

    // ---- final layer: hb @ [W2|wl2|wr2] + hb @ resW2 (M=47) ----
    gemm_mfma<false, 4, 3, 1><<<gemmBlocks, 256, 0, stream>>>(
        hb, W2t, rW2t, featb, el, er, resb, NN, 128, NC);
    edge_e<1><<<edgeBlocks, 256, 0, stream>>>(el, er, src, dst, e2, NE);
    node_agg1<<<nodeBlocks, 256, 0, stream>>>(
        featb, el, er, es, offs, srcs, resb, logits);
}